// Round 1
// baseline (176.258 us; speedup 1.0000x reference)
//
#include <hip/hip_runtime.h>
#include <hip/hip_bf16.h>

#define BB 128
#define TT 1024
#define ENC_DIM 512
#define QUERY_DIM 1024
#define ATT_DIM 128
#define ATT_FILTERS 32
#define ATT_KERNEL 31
#define TILE_T 128

__device__ __forceinline__ float tanh_fast(float x) {
    // tanh(x) = 1 - 2/(1+exp(2x)); handles +-inf limits correctly.
    float e = __expf(2.0f * x);
    return 1.0f - 2.0f * __builtin_amdgcn_rcpf(1.0f + e);
}

// K1: pq[b][a] = sum_k query[b][k] * Wq[k][a]
__global__ __launch_bounds__(128) void k_pq(const float* __restrict__ query,
                                            const float* __restrict__ Wq,
                                            float* __restrict__ pq) {
    __shared__ float q[QUERY_DIM];
    int b = blockIdx.x;
    int a = threadIdx.x;
    for (int k = a; k < QUERY_DIM; k += 128) q[k] = query[b * QUERY_DIM + k];
    __syncthreads();
    float acc = 0.f;
#pragma unroll 8
    for (int k = 0; k < QUERY_DIM; ++k) acc += q[k] * Wq[k * ATT_DIM + a];
    pq[b * ATT_DIM + a] = acc;
}

// K2: energies[b][t] = tanh(pq + conv(aw)@Wloc + pm) . v
__global__ __launch_bounds__(256) void k_energy(
    const float* __restrict__ aw,    // (B,T,2)
    const float* __restrict__ ck,    // (31,2,32)
    const float* __restrict__ Wloc,  // (32,128)
    const float* __restrict__ pm,    // (B,T,128)
    const float* __restrict__ pq,    // (B,128)
    const float* __restrict__ v,     // (128)
    float* __restrict__ energies)    // (B,T)
{
    __shared__ float s_aw[(TILE_T + 30) * 2];
    __shared__ float s_ck[ATT_KERNEL * 2 * ATT_FILTERS];
    __shared__ float s_f[TILE_T * ATT_FILTERS];

    int b = blockIdx.y;
    int t0 = blockIdx.x * TILE_T;
    int tid = threadIdx.x;

    for (int i = tid; i < ATT_KERNEL * 2 * ATT_FILTERS; i += 256) s_ck[i] = ck[i];
    for (int i = tid; i < (TILE_T + 30) * 2; i += 256) {
        int ii = i >> 1, c = i & 1;
        int t = t0 - 15 + ii;
        s_aw[i] = (t >= 0 && t < TT) ? aw[(b * TT + t) * 2 + c] : 0.f;
    }
    __syncthreads();

    // conv features: f[t][j], t in tile, j filter
    for (int idx = tid; idx < TILE_T * ATT_FILTERS; idx += 256) {
        int t = idx >> 5, j = idx & 31;
        float acc = 0.f;
#pragma unroll
        for (int k = 0; k < ATT_KERNEL; ++k) {
            acc += s_aw[(t + k) * 2]     * s_ck[k * 64 + j];
            acc += s_aw[(t + k) * 2 + 1] * s_ck[k * 64 + 32 + j];
        }
        s_f[t * ATT_FILTERS + j] = acc;
    }
    __syncthreads();

    int w = tid >> 6, lane = tid & 63;
    int a0 = lane, a1 = lane + 64;

    float wl0[ATT_FILTERS], wl1[ATT_FILTERS];
#pragma unroll
    for (int j = 0; j < ATT_FILTERS; ++j) {
        wl0[j] = Wloc[j * ATT_DIM + a0];
        wl1[j] = Wloc[j * ATT_DIM + a1];
    }
    float pq0 = pq[b * ATT_DIM + a0], pq1 = pq[b * ATT_DIM + a1];
    float v0 = v[a0], v1 = v[a1];

    for (int t = w; t < TILE_T; t += 4) {
        long base = ((long)(b * TT + t0 + t)) * ATT_DIM;
        float x0 = pq0 + pm[base + a0];
        float x1 = pq1 + pm[base + a1];
        const float4* f4 = reinterpret_cast<const float4*>(&s_f[t * ATT_FILTERS]);
#pragma unroll
        for (int j4 = 0; j4 < ATT_FILTERS / 4; ++j4) {
            float4 f = f4[j4];
            x0 += f.x * wl0[4 * j4] + f.y * wl0[4 * j4 + 1] + f.z * wl0[4 * j4 + 2] + f.w * wl0[4 * j4 + 3];
            x1 += f.x * wl1[4 * j4] + f.y * wl1[4 * j4 + 1] + f.z * wl1[4 * j4 + 2] + f.w * wl1[4 * j4 + 3];
        }
        float e = tanh_fast(x0) * v0 + tanh_fast(x1) * v1;
#pragma unroll
        for (int off = 32; off > 0; off >>= 1) e += __shfl_xor(e, off);
        if (lane == 0) energies[b * TT + t0 + t] = e;
    }
}

// K3: softmax over T, in place
__global__ __launch_bounds__(256) void k_softmax(float* __restrict__ wts) {
    __shared__ float red[4];
    __shared__ float red2[4];
    int b = blockIdx.x;
    int tid = threadIdx.x;
    float* row = wts + b * TT;
    float vals[4];
    float m = -1e30f;
#pragma unroll
    for (int i = 0; i < 4; ++i) {
        vals[i] = row[tid + i * 256];
        m = fmaxf(m, vals[i]);
    }
#pragma unroll
    for (int off = 32; off > 0; off >>= 1) m = fmaxf(m, __shfl_xor(m, off));
    int wv = tid >> 6, lane = tid & 63;
    if (lane == 0) red[wv] = m;
    __syncthreads();
    m = fmaxf(fmaxf(red[0], red[1]), fmaxf(red[2], red[3]));
    float s = 0.f;
#pragma unroll
    for (int i = 0; i < 4; ++i) {
        vals[i] = __expf(vals[i] - m);
        s += vals[i];
    }
#pragma unroll
    for (int off = 32; off > 0; off >>= 1) s += __shfl_xor(s, off);
    if (lane == 0) red2[wv] = s;
    __syncthreads();
    s = red2[0] + red2[1] + red2[2] + red2[3];
    float inv = 1.0f / s;
#pragma unroll
    for (int i = 0; i < 4; ++i) row[tid + i * 256] = vals[i] * inv;
}

// K4: context[b][d] = sum_t wts[b][t] * mem[b][t][d]
__global__ __launch_bounds__(256) void k_context(
    const float* __restrict__ wts,   // (B,T)
    const float* __restrict__ mem,   // (B,T,ENC)
    float* __restrict__ ctx)         // (B,ENC)
{
    int b = blockIdx.y;
    int d = blockIdx.x * 256 + threadIdx.x;
    const float* wr = wts + b * TT;
    const float* mr = mem + (long)b * TT * ENC_DIM + d;
    float acc = 0.f;
#pragma unroll 16
    for (int t = 0; t < TT; ++t) {
        acc += wr[t] * mr[(long)t * ENC_DIM];
    }
    ctx[b * ENC_DIM + d] = acc;
}

extern "C" void kernel_launch(void* const* d_in, const int* in_sizes, int n_in,
                              void* d_out, int out_size, void* d_ws, size_t ws_size,
                              hipStream_t stream) {
    const float* query  = (const float*)d_in[0];
    const float* memory = (const float*)d_in[1];
    const float* pm     = (const float*)d_in[2];
    const float* awc    = (const float*)d_in[3];
    const float* Wq     = (const float*)d_in[4];
    const float* ck     = (const float*)d_in[5];
    const float* Wloc   = (const float*)d_in[6];
    const float* v      = (const float*)d_in[7];

    float* out = (float*)d_out;
    float* ctx = out;                       // (B, ENC_DIM)
    float* wts = out + BB * ENC_DIM;        // (B, T) — energies then softmax in place
    float* pq  = (float*)d_ws;              // (B, ATT_DIM)

    k_pq<<<dim3(BB), dim3(128), 0, stream>>>(query, Wq, pq);
    k_energy<<<dim3(TT / TILE_T, BB), dim3(256), 0, stream>>>(awc, ck, Wloc, pm, pq, v, wts);
    k_softmax<<<dim3(BB), dim3(256), 0, stream>>>(wts);
    k_context<<<dim3(ENC_DIM / 256, BB), dim3(256), 0, stream>>>(wts, memory, ctx);
}

// Round 2
// 144.018 us; speedup vs baseline: 1.2239x; 1.2239x over previous
//
#include <hip/hip_runtime.h>
#include <hip/hip_bf16.h>

#define BB 128
#define TT 1024
#define ENC_DIM 512
#define QUERY_DIM 1024
#define ATT_DIM 128
#define ATT_FILTERS 32
#define ATT_KERNEL 31
#define TILE_T 128
#define TSPLIT 8
#define TCH (TT / TSPLIT)   // 128 t per context block

__device__ __forceinline__ float tanh_fast(float x) {
    float e = __expf(2.0f * x);
    return 1.0f - 2.0f * __builtin_amdgcn_rcpf(1.0f + e);
}

// K1: pq partials. grid (B, 2): blockIdx.y = k-half. 256 thr: a=tid&127, ks=tid>>7.
// pqp[(h*B + b)*128 + a] = sum over 512 k of q*Wq
__global__ __launch_bounds__(256) void k_pq(const float* __restrict__ query,
                                            const float* __restrict__ Wq,
                                            float* __restrict__ pqp) {
    __shared__ float q[512];
    __shared__ float pp[128];
    int b = blockIdx.x, h = blockIdx.y;
    int tid = threadIdx.x, a = tid & 127, ks = tid >> 7;
    for (int i = tid; i < 512; i += 256) q[i] = query[b * QUERY_DIM + h * 512 + i];
    __syncthreads();
    const float* w = Wq + (h * 512 + ks * 256) * ATT_DIM + a;
    const float* qs = q + ks * 256;
    float acc = 0.f;
#pragma unroll 16
    for (int k = 0; k < 256; ++k) acc += qs[k] * w[k * ATT_DIM];
    if (ks) pp[a] = acc;
    __syncthreads();
    if (!ks) pqp[(h * BB + b) * ATT_DIM + a] = acc + pp[a];
}

// K2: energies[b][t] = tanh(pq + conv(aw)@Wloc + pm) . v
__global__ __launch_bounds__(256) void k_energy(
    const float* __restrict__ aw,    // (B,T,2)
    const float* __restrict__ ck,    // (31,2,32)
    const float* __restrict__ Wloc,  // (32,128)
    const float* __restrict__ pm,    // (B,T,128)
    const float* __restrict__ pqp,   // (2,B,128)
    const float* __restrict__ v,     // (128)
    float* __restrict__ energies)    // (B,T)
{
    __shared__ float s_aw[(TILE_T + 30) * 2];
    __shared__ float s_ck[ATT_KERNEL * 2 * ATT_FILTERS];
    __shared__ float s_f[TILE_T * ATT_FILTERS];

    int b = blockIdx.y;
    int t0 = blockIdx.x * TILE_T;
    int tid = threadIdx.x;

    for (int i = tid; i < ATT_KERNEL * 2 * ATT_FILTERS; i += 256) s_ck[i] = ck[i];
    for (int i = tid; i < (TILE_T + 30) * 2; i += 256) {
        int ii = i >> 1, c = i & 1;
        int t = t0 - 15 + ii;
        s_aw[i] = (t >= 0 && t < TT) ? aw[(b * TT + t) * 2 + c] : 0.f;
    }
    __syncthreads();

    // conv: j fixed per thread, weights register-cached, aw pair as float2
    {
        int j = tid & 31;
        float wk0[ATT_KERNEL], wk1[ATT_KERNEL];
#pragma unroll
        for (int k = 0; k < ATT_KERNEL; ++k) {
            wk0[k] = s_ck[k * 64 + j];
            wk1[k] = s_ck[k * 64 + 32 + j];
        }
        for (int t = tid >> 5; t < TILE_T; t += 8) {
            float acc0 = 0.f, acc1 = 0.f;
#pragma unroll
            for (int k = 0; k < ATT_KERNEL; ++k) {
                float2 awp = *reinterpret_cast<const float2*>(&s_aw[(t + k) * 2]);
                acc0 += awp.x * wk0[k];
                acc1 += awp.y * wk1[k];
            }
            s_f[t * ATT_FILTERS + j] = acc0 + acc1;
        }
    }
    __syncthreads();

    int w = tid >> 6, lane = tid & 63;
    int a0 = lane, a1 = lane + 64;

    float wl0[ATT_FILTERS], wl1[ATT_FILTERS];
#pragma unroll
    for (int j = 0; j < ATT_FILTERS; ++j) {
        wl0[j] = Wloc[j * ATT_DIM + a0];
        wl1[j] = Wloc[j * ATT_DIM + a1];
    }
    float pq0 = pqp[b * ATT_DIM + a0] + pqp[(BB + b) * ATT_DIM + a0];
    float pq1 = pqp[b * ATT_DIM + a1] + pqp[(BB + b) * ATT_DIM + a1];
    float v0 = v[a0], v1 = v[a1];

    long base0 = ((long)(b * TT + t0 + w)) * ATT_DIM;
    float c0 = pm[base0 + a0], c1 = pm[base0 + a1];

    for (int t = w; t < TILE_T; t += 4) {
        float x0 = pq0 + c0;
        float x1 = pq1 + c1;
        if (t + 4 < TILE_T) {   // prefetch next pm element
            long nb = ((long)(b * TT + t0 + t + 4)) * ATT_DIM;
            c0 = pm[nb + a0];
            c1 = pm[nb + a1];
        }
        const float4* f4 = reinterpret_cast<const float4*>(&s_f[t * ATT_FILTERS]);
#pragma unroll
        for (int j4 = 0; j4 < ATT_FILTERS / 4; ++j4) {
            float4 f = f4[j4];
            x0 += f.x * wl0[4 * j4] + f.y * wl0[4 * j4 + 1] + f.z * wl0[4 * j4 + 2] + f.w * wl0[4 * j4 + 3];
            x1 += f.x * wl1[4 * j4] + f.y * wl1[4 * j4 + 1] + f.z * wl1[4 * j4 + 2] + f.w * wl1[4 * j4 + 3];
        }
        float e = tanh_fast(x0) * v0 + tanh_fast(x1) * v1;
#pragma unroll
        for (int off = 32; off > 0; off >>= 1) e += __shfl_xor(e, off);
        if (lane == 0) energies[b * TT + t0 + t] = e;
    }
}

// K4: fused softmax + partial context. grid (TSPLIT, B), 256 thr.
__global__ __launch_bounds__(256) void k_ctx(
    const float* __restrict__ energies, // (B,T)
    const float* __restrict__ mem,      // (B,T,ENC)
    float* __restrict__ wts_out,        // (B,T) final weights
    float* __restrict__ part)           // (TSPLIT,B,ENC)
{
    __shared__ float sw[TT];
    __shared__ float red[4], red2[4];
    int s = blockIdx.x, b = blockIdx.y;
    int tid = threadIdx.x, w = tid >> 6, lane = tid & 63;

    // softmax stats over the full row (redundant per block, identical arithmetic)
    float4 ev = reinterpret_cast<const float4*>(energies + b * TT)[tid];
    float m = fmaxf(fmaxf(ev.x, ev.y), fmaxf(ev.z, ev.w));
#pragma unroll
    for (int off = 32; off > 0; off >>= 1) m = fmaxf(m, __shfl_xor(m, off));
    if (lane == 0) red[w] = m;
    __syncthreads();
    m = fmaxf(fmaxf(red[0], red[1]), fmaxf(red[2], red[3]));
    float4 x;
    x.x = __expf(ev.x - m); x.y = __expf(ev.y - m);
    x.z = __expf(ev.z - m); x.w = __expf(ev.w - m);
    float ssum = x.x + x.y + x.z + x.w;
#pragma unroll
    for (int off = 32; off > 0; off >>= 1) ssum += __shfl_xor(ssum, off);
    if (lane == 0) red2[w] = ssum;
    __syncthreads();
    ssum = red2[0] + red2[1] + red2[2] + red2[3];
    float inv = 1.0f / ssum;
    x.x *= inv; x.y *= inv; x.z *= inv; x.w *= inv;
    reinterpret_cast<float4*>(sw)[tid] = x;
    if ((tid >> 5) == s)   // this block's chunk of the weights output
        reinterpret_cast<float4*>(wts_out + b * TT)[tid] = x;
    __syncthreads();

    // partial context over this block's t-chunk
    int p = tid >> 7, q = tid & 127;
    const float4* m4 = reinterpret_cast<const float4*>(mem + ((long)(b * TT + s * TCH)) * ENC_DIM) + q;
    float4 acc = {0.f, 0.f, 0.f, 0.f};
#pragma unroll 8
    for (int t = p; t < TCH; t += 2) {
        float wt = sw[s * TCH + t];
        float4 mv = m4[(long)t * (ENC_DIM / 4)];
        acc.x += wt * mv.x; acc.y += wt * mv.y;
        acc.z += wt * mv.z; acc.w += wt * mv.w;
    }
    __syncthreads();
    if (p == 1) reinterpret_cast<float4*>(sw)[q] = acc;
    __syncthreads();
    if (p == 0) {
        float4 o = reinterpret_cast<float4*>(sw)[q];
        acc.x += o.x; acc.y += o.y; acc.z += o.z; acc.w += o.w;
        reinterpret_cast<float4*>(part)[(s * BB + b) * (ENC_DIM / 4) + q] = acc;
    }
}

// K5: ctx[b][d] = sum_s part[s][b][d]
__global__ __launch_bounds__(256) void k_reduce(const float* __restrict__ part,
                                               float* __restrict__ ctx) {
    int i = blockIdx.x * 256 + threadIdx.x;   // 65536 outputs
    float a = 0.f;
#pragma unroll
    for (int s = 0; s < TSPLIT; ++s) a += part[s * BB * ENC_DIM + i];
    ctx[i] = a;
}

extern "C" void kernel_launch(void* const* d_in, const int* in_sizes, int n_in,
                              void* d_out, int out_size, void* d_ws, size_t ws_size,
                              hipStream_t stream) {
    const float* query  = (const float*)d_in[0];
    const float* memory = (const float*)d_in[1];
    const float* pm     = (const float*)d_in[2];
    const float* awc    = (const float*)d_in[3];
    const float* Wq     = (const float*)d_in[4];
    const float* ck     = (const float*)d_in[5];
    const float* Wloc   = (const float*)d_in[6];
    const float* v      = (const float*)d_in[7];

    float* out = (float*)d_out;
    float* ctx = out;                       // (B, ENC_DIM)
    float* wts = out + BB * ENC_DIM;        // (B, T)

    float* pqp      = (float*)d_ws;                       // (2, B, 128)
    float* energies = pqp + 2 * BB * ATT_DIM;             // (B, T)
    float* part     = energies + BB * TT;                 // (TSPLIT, B, ENC)

    k_pq<<<dim3(BB, 2), dim3(256), 0, stream>>>(query, Wq, pqp);
    k_energy<<<dim3(TT / TILE_T, BB), dim3(256), 0, stream>>>(awc, ck, Wloc, pm, pqp, v, energies);
    k_ctx<<<dim3(TSPLIT, BB), dim3(256), 0, stream>>>(energies, memory, wts, part);
    k_reduce<<<dim3(BB * ENC_DIM / 256), dim3(256), 0, stream>>>(part, ctx);
}